// Round 1
// baseline (192.948 us; speedup 1.0000x reference)
//
#include <hip/hip_runtime.h>

#define NROWS 8192
#define HALF_N 4096
#define DIM 512
#define INV_T 10.0f

typedef __attribute__((ext_vector_type(8))) short short8;
typedef __attribute__((ext_vector_type(4))) float f32x4;

__device__ __forceinline__ ushort f32_to_bf16_rne(float x) {
  unsigned u = __float_as_uint(x);
  unsigned r = (u + 0x7fffu + ((u >> 16) & 1u)) >> 16;
  return (ushort)r;
}

// Kernel 1: L2-normalize each row (fp32), cast to bf16, store to ws.
// One wave per row. Also zero-inits rowsum (ws is 0xAA-poisoned each launch).
__global__ __launch_bounds__(64) void norm_cast_k(
    const float* __restrict__ f1, const float* __restrict__ f2,
    ushort* __restrict__ Fn, float* __restrict__ rowsum) {
  int row = blockIdx.x;
  int lane = threadIdx.x;
  const float* src = (row < HALF_N) ? (f1 + (size_t)row * DIM)
                                    : (f2 + (size_t)(row - HALF_N) * DIM);
  const float4* p = reinterpret_cast<const float4*>(src + lane * 8);
  float4 v0 = p[0];
  float4 v1 = p[1];
  float ss = v0.x*v0.x + v0.y*v0.y + v0.z*v0.z + v0.w*v0.w
           + v1.x*v1.x + v1.y*v1.y + v1.z*v1.z + v1.w*v1.w;
  #pragma unroll
  for (int off = 1; off < 64; off <<= 1) ss += __shfl_xor(ss, off);
  float scale = 1.0f / fmaxf(sqrtf(ss), 1e-12f);
  union { ushort u[8]; short8 v; } o;
  o.u[0] = f32_to_bf16_rne(v0.x * scale);
  o.u[1] = f32_to_bf16_rne(v0.y * scale);
  o.u[2] = f32_to_bf16_rne(v0.z * scale);
  o.u[3] = f32_to_bf16_rne(v0.w * scale);
  o.u[4] = f32_to_bf16_rne(v1.x * scale);
  o.u[5] = f32_to_bf16_rne(v1.y * scale);
  o.u[6] = f32_to_bf16_rne(v1.z * scale);
  o.u[7] = f32_to_bf16_rne(v1.w * scale);
  *reinterpret_cast<short8*>(Fn + (size_t)row * DIM + lane * 8) = o.v;
  if (lane == 0) rowsum[row] = 0.0f;
}

// Kernel 2: fused sim-GEMM + exp-accumulate.
// Grid: 512 blocks = 64 row-blocks (128 rows) x 8 col-slices (1024 cols).
// slice = bx & 7 so same-slice blocks share an XCD's L2 (bx%8 ~ XCD).
// Each wave owns 32 rows (2 x 16-row MFMA tiles), A-fragments in registers.
// B tiles (64 cols x 512 k) staged in 64 KB LDS with XOR chunk swizzle.
__global__ __launch_bounds__(256, 2) void infonce_main_k(
    const ushort* __restrict__ Fn, float* __restrict__ rowsum,
    float* __restrict__ pairsim) {
  const int bx = blockIdx.x;
  const int slice = bx & 7;
  const int rb = bx >> 3;
  const int row0 = rb * 128;
  const int tid = threadIdx.x;
  const int wave = tid >> 6;
  const int lane = tid & 63;
  const int quad = lane >> 4;
  const int col = lane & 15;
  const int wrow = row0 + wave * 32;   // this wave's first row

  __shared__ ushort Bt[64 * 512];      // 64 KB, swizzled: chunk ch of row r at (ch ^ (r&7))

  // Load A fragments: a[t][kk] covers rows [wrow + t*16, +16), k in [kk*32, +32)
  // A layout (16x16x32): m = lane&15, k = quad*8 + j  (8 contiguous bf16)
  short8 a[2][16];
  #pragma unroll
  for (int t = 0; t < 2; ++t) {
    const ushort* rp = Fn + (size_t)(wrow + t * 16 + col) * DIM;
    #pragma unroll
    for (int kk = 0; kk < 16; ++kk)
      a[t][kk] = *reinterpret_cast<const short8*>(rp + kk * 32 + quad * 8);
  }

  float accexp[2][4];
  float accpair[2][4];
  #pragma unroll
  for (int t = 0; t < 2; ++t)
    #pragma unroll
    for (int r = 0; r < 4; ++r) { accexp[t][r] = 0.0f; accpair[t][r] = 0.0f; }

  const int j0 = slice * 1024;
  for (int it = 0; it < 16; ++it) {
    const int c0 = j0 + it * 64;       // global col base of this 64-col tile
    __syncthreads();                   // protect prior iteration's LDS reads
    // Stage B tile: 64 rows x 1 KB. Each wave loads one full row per round
    // (coalesced 1 KB), writes with XOR-swizzled chunk index.
    #pragma unroll
    for (int rnd = 0; rnd < 16; ++rnd) {
      int s = rnd * 256 + tid;
      int r = s >> 6;                  // 0..63 (constant per wave)
      int ch = s & 63;                 // = lane
      const uint4* gp = reinterpret_cast<const uint4*>(
          Fn + (size_t)(c0 + r) * DIM + ch * 8);
      uint4 v = *gp;
      *reinterpret_cast<uint4*>(&Bt[r * 512 + ((ch ^ (r & 7)) * 8)]) = v;
    }
    __syncthreads();

    // 4 col sub-tiles of 16
    for (int cs = 0; cs < 4; ++cs) {
      const int bcol0 = cs * 16;
      f32x4 acc0 = {0.f, 0.f, 0.f, 0.f};
      f32x4 acc1 = {0.f, 0.f, 0.f, 0.f};
      const int lr = bcol0 + col;      // local B row (= local col of C)
      #pragma unroll
      for (int kk = 0; kk < 16; ++kk) {
        int chunk = kk * 4 + quad;     // 16B chunk index within row
        short8 b = *reinterpret_cast<const short8*>(
            &Bt[lr * 512 + ((chunk ^ (lr & 7)) * 8)]);
        acc0 = __builtin_amdgcn_mfma_f32_16x16x32_bf16(a[0][kk], b, acc0, 0, 0, 0);
        acc1 = __builtin_amdgcn_mfma_f32_16x16x32_bf16(a[1][kk], b, acc1, 0, 0, 0);
      }
      // Epilogue: C/D layout col = lane&15, row = quad*4 + reg (m89-verified)
      const int gc = c0 + bcol0 + col; // global col of this lane's outputs
      #pragma unroll
      for (int t = 0; t < 2; ++t) {
        f32x4 accv = t ? acc1 : acc0;
        const int trow = wrow + t * 16;
        #pragma unroll
        for (int r = 0; r < 4; ++r) {
          int grow = trow + quad * 4 + r;
          float simv = accv[r] * INV_T;
          float e = (grow == gc) ? 0.0f : __expf(simv);  // mask diagonal
          accexp[t][r] += e;
          if (gc == (grow ^ HALF_N)) accpair[t][r] += simv;  // positive pair
        }
      }
    }
  }

  // Reduce across the 16 lanes holding one row's 16 cols
  #pragma unroll
  for (int off = 1; off < 16; off <<= 1) {
    #pragma unroll
    for (int t = 0; t < 2; ++t)
      #pragma unroll
      for (int r = 0; r < 4; ++r) {
        accexp[t][r] += __shfl_xor(accexp[t][r], off);
        accpair[t][r] += __shfl_xor(accpair[t][r], off);
      }
  }
  if (col == 0) {
    #pragma unroll
    for (int t = 0; t < 2; ++t)
      #pragma unroll
      for (int r = 0; r < 4; ++r) {
        int grow = wrow + t * 16 + quad * 4 + r;
        atomicAdd(&rowsum[grow], accexp[t][r]);
        // exactly one slice contains this row's pair column -> unique writer
        if (((grow ^ HALF_N) >> 10) == slice) pairsim[grow] = accpair[t][r];
      }
  }
}

// Kernel 3: loss = mean_i( log(rowsum_i) - pair_i ). Single block.
__global__ __launch_bounds__(1024) void finalize_k(
    const float* __restrict__ rowsum, const float* __restrict__ pairsim,
    float* __restrict__ out) {
  float local = 0.0f;
  for (int i = threadIdx.x; i < NROWS; i += 1024)
    local += logf(rowsum[i]) - pairsim[i];
  #pragma unroll
  for (int off = 1; off < 64; off <<= 1) local += __shfl_xor(local, off);
  __shared__ float red[16];
  int wave = threadIdx.x >> 6;
  int lane = threadIdx.x & 63;
  if (lane == 0) red[wave] = local;
  __syncthreads();
  if (threadIdx.x == 0) {
    float s = 0.0f;
    #pragma unroll
    for (int w = 0; w < 16; ++w) s += red[w];
    out[0] = s * (1.0f / (float)NROWS);
  }
}

extern "C" void kernel_launch(void* const* d_in, const int* in_sizes, int n_in,
                              void* d_out, int out_size, void* d_ws, size_t ws_size,
                              hipStream_t stream) {
  const float* f1 = (const float*)d_in[0];
  const float* f2 = (const float*)d_in[1];
  ushort* Fn = (ushort*)d_ws;                                   // 8192*512 bf16 = 8 MB
  float* rowsum = (float*)((char*)d_ws + (size_t)NROWS * DIM * 2);
  float* pairsim = rowsum + NROWS;
  float* out = (float*)d_out;

  norm_cast_k<<<NROWS, 64, 0, stream>>>(f1, f2, Fn, rowsum);
  infonce_main_k<<<512, 256, 0, stream>>>(Fn, rowsum, pairsim);
  finalize_k<<<1, 1024, 0, stream>>>(rowsum, pairsim, out);
}

// Round 2
// 126.859 us; speedup vs baseline: 1.5210x; 1.5210x over previous
//
#include <hip/hip_runtime.h>

#define NROWS 8192
#define HALF_N 4096
#define DIM 512
#define INV_T 10.0f
#define NRB 64              // number of 128-row blocks
#define NBLOCKS 2080        // 64*65/2 upper-triangle block pairs

typedef __attribute__((ext_vector_type(8))) short short8;
typedef __attribute__((ext_vector_type(4))) float f32x4;

__device__ __forceinline__ ushort f32_to_bf16_rne(float x) {
  unsigned u = __float_as_uint(x);
  unsigned r = (u + 0x7fffu + ((u >> 16) & 1u)) >> 16;
  return (ushort)r;
}

// async 16B global -> LDS (DMA, no VGPR round trip). LDS dest is
// wave-uniform base + lane*16; global src is per-lane.
__device__ __forceinline__ void async16(const void* g, void* l) {
  __builtin_amdgcn_global_load_lds(
      (const __attribute__((address_space(1))) unsigned int*)g,
      (__attribute__((address_space(3))) unsigned int*)l, 16, 0, 0);
}

// Kernel 1: L2-normalize rows of [f1;f2] -> bf16 Fn; zero rowsum.
// 256 threads = 4 waves, one row per wave.
__global__ __launch_bounds__(256) void norm_cast_k(
    const float* __restrict__ f1, const float* __restrict__ f2,
    ushort* __restrict__ Fn, float* __restrict__ rowsum) {
  int wave = threadIdx.x >> 6;
  int lane = threadIdx.x & 63;
  int row = blockIdx.x * 4 + wave;
  const float* src = (row < HALF_N) ? (f1 + (size_t)row * DIM)
                                    : (f2 + (size_t)(row - HALF_N) * DIM);
  const float4* p = reinterpret_cast<const float4*>(src + lane * 8);
  float4 v0 = p[0];
  float4 v1 = p[1];
  float ss = v0.x*v0.x + v0.y*v0.y + v0.z*v0.z + v0.w*v0.w
           + v1.x*v1.x + v1.y*v1.y + v1.z*v1.z + v1.w*v1.w;
  #pragma unroll
  for (int off = 1; off < 64; off <<= 1) ss += __shfl_xor(ss, off);
  float scale = 1.0f / fmaxf(sqrtf(ss), 1e-12f);
  union { ushort u[8]; short8 v; } o;
  o.u[0] = f32_to_bf16_rne(v0.x * scale);
  o.u[1] = f32_to_bf16_rne(v0.y * scale);
  o.u[2] = f32_to_bf16_rne(v0.z * scale);
  o.u[3] = f32_to_bf16_rne(v0.w * scale);
  o.u[4] = f32_to_bf16_rne(v1.x * scale);
  o.u[5] = f32_to_bf16_rne(v1.y * scale);
  o.u[6] = f32_to_bf16_rne(v1.z * scale);
  o.u[7] = f32_to_bf16_rne(v1.w * scale);
  *reinterpret_cast<short8*>(Fn + (size_t)row * DIM + lane * 8) = o.v;
  if (lane == 0) rowsum[row] = 0.0f;
}

// Kernel 2: symmetric upper-triangle sim GEMM, fused exp row+col accumulation.
// Grid: 2080 blocks = (rb, cb) with cb >= rb, 128x128 output tiles.
// m97 structure: K streamed in BK=32 rounds, A/B tiles (8 KB each) staged via
// global_load_lds, 4 waves each computing a 64x64 register tile.
__global__ __launch_bounds__(256, 3) void sym_gemm_k(
    const ushort* __restrict__ Fn, float* __restrict__ rowsum,
    float* __restrict__ pairsim) {
  // XCD-contiguous remap: each XCD (bx%8) gets a contiguous 260-block range
  int bx = blockIdx.x;
  int gbx = (bx & 7) * (NBLOCKS / 8) + (bx >> 3);
  int rb = 0, rem = gbx;
  while (rem >= NRB - rb) { rem -= NRB - rb; ++rb; }
  const int cb = rb + rem;
  const int row0 = rb * 128, col0 = cb * 128;

  const int tid = threadIdx.x;
  const int wave = tid >> 6;
  const int lane = tid & 63;
  const int quad = lane >> 4;
  const int colid = lane & 15;
  const int wr0 = (wave >> 1) * 64;   // wave's row offset within tile
  const int wc0 = (wave & 1) * 64;    // wave's col offset within tile

  // LDS tiles: 128 rows x 32 k bf16 = 64 B/row, 4 x 16B chunks per row.
  // Physical chunk = logical ^ ((row>>1)&3)  -> conflict-free frag reads.
  __shared__ ushort Alds[128 * 32];
  __shared__ ushort Blds[128 * 32];
  __shared__ float redrow[128];
  __shared__ float redcol[128];

  if (tid < 128) { redrow[tid] = 0.0f; redcol[tid] = 0.0f; }

  // Staging: 16 x 1KB wave-instructions per round (8 A + 8 B), wave w owns
  // A insts {w, w+4} and B insts {w, w+4}. Inst i covers rows [i*16, i*16+16).
  // lane -> local row r = i*16 + (lane>>2), physical chunk p = lane&3;
  // global source uses logical chunk c = p ^ ((r>>1)&3) (swizzle inverse).
  const char* FnB = (const char*)Fn;
  const char* srcA[2]; const char* srcB[2];
  ushort* dstA[2]; ushort* dstB[2];
  #pragma unroll
  for (int seg = 0; seg < 2; ++seg) {
    int inst = wave + seg * 4;
    int r = inst * 16 + (lane >> 2);
    int c = (lane & 3) ^ ((r >> 1) & 3);
    srcA[seg] = FnB + (size_t)(row0 + r) * (DIM * 2) + c * 16;
    srcB[seg] = FnB + (size_t)(col0 + r) * (DIM * 2) + c * 16;
    dstA[seg] = Alds + inst * 512;   // 1 KB per inst
    dstB[seg] = Blds + inst * 512;
  }

  // Fragment LDS addresses (constant across rounds).
  // A operand (16x16x32): lane holds A[m = lane&15][k = quad*8 + j].
  const ushort* afp[4]; const ushort* bfp[4];
  #pragma unroll
  for (int t = 0; t < 4; ++t) {
    int r = wr0 + t * 16 + colid;
    afp[t] = Alds + r * 32 + (quad ^ ((r >> 1) & 3)) * 8;
    int c = wc0 + t * 16 + colid;
    bfp[t] = Blds + c * 32 + (quad ^ ((c >> 1) & 3)) * 8;
  }

  f32x4 acc[4][4];
  #pragma unroll
  for (int t = 0; t < 4; ++t)
    #pragma unroll
    for (int u = 0; u < 4; ++u) acc[t][u] = (f32x4){0.f, 0.f, 0.f, 0.f};

  for (int kc = 0; kc < 16; ++kc) {
    __syncthreads();                   // prior round's reads done
    const int koff = kc * 64;          // 32 k-elems = 64 bytes per row
    #pragma unroll
    for (int seg = 0; seg < 2; ++seg) {
      async16(srcA[seg] + koff, dstA[seg]);
      async16(srcB[seg] + koff, dstB[seg]);
    }
    __syncthreads();                   // drains vmcnt -> tiles visible

    short8 af[4], bf[4];
    #pragma unroll
    for (int t = 0; t < 4; ++t) af[t] = *reinterpret_cast<const short8*>(afp[t]);
    #pragma unroll
    for (int t = 0; t < 4; ++t) bf[t] = *reinterpret_cast<const short8*>(bfp[t]);
    #pragma unroll
    for (int t = 0; t < 4; ++t)
      #pragma unroll
      for (int u = 0; u < 4; ++u)
        acc[t][u] = __builtin_amdgcn_mfma_f32_16x16x32_bf16(af[t], bf[u], acc[t][u], 0, 0, 0);
  }

  // Epilogue. C/D layout: col = lane&15, row = quad*4 + reg (m89-verified).
  float re[4][4];                      // per (t, reg): sum over ct + this col
  float ce[4];                         // per ct: sum over t,reg for this col
  #pragma unroll
  for (int t = 0; t < 4; ++t)
    #pragma unroll
    for (int r = 0; r < 4; ++r) re[t][r] = 0.0f;
  #pragma unroll
  for (int u = 0; u < 4; ++u) ce[u] = 0.0f;

  #pragma unroll
  for (int t = 0; t < 4; ++t) {
    #pragma unroll
    for (int u = 0; u < 4; ++u) {
      f32x4 a = acc[t][u];
      const int gc = col0 + wc0 + u * 16 + colid;
      #pragma unroll
      for (int r = 0; r < 4; ++r) {
        int grow = row0 + wr0 + t * 16 + quad * 4 + r;
        float sim = a[r] * INV_T;
        float e = (gc > grow) ? __expf(sim) : 0.0f;  // strict upper triangle
        re[t][r] += e;
        ce[u] += e;
        if (gc == grow + HALF_N && grow < HALF_N) {
          pairsim[grow] = sim;         // unique writer per pair
          pairsim[gc] = sim;
        }
      }
    }
  }

  // Row sums: reduce across the 16 col-lanes, LDS-accumulate.
  #pragma unroll
  for (int t = 0; t < 4; ++t)
    #pragma unroll
    for (int r = 0; r < 4; ++r) {
      float v = re[t][r];
      v += __shfl_xor(v, 1); v += __shfl_xor(v, 2);
      v += __shfl_xor(v, 4); v += __shfl_xor(v, 8);
      if (colid == 0) atomicAdd(&redrow[wr0 + t * 16 + quad * 4 + r], v);
    }
  // Col sums: reduce across the 4 quads (this wave's 64 rows).
  #pragma unroll
  for (int u = 0; u < 4; ++u) {
    float v = ce[u];
    v += __shfl_xor(v, 16); v += __shfl_xor(v, 32);
    if (lane < 16) atomicAdd(&redcol[wc0 + u * 16 + colid], v);
  }
  __syncthreads();
  if (tid < 128) atomicAdd(&rowsum[row0 + tid], redrow[tid]);
  else           atomicAdd(&rowsum[col0 + tid - 128], redcol[tid - 128]);
}

// Kernel 3: loss = mean_i( log(rowsum_i) - pairsim_i ). Single block.
__global__ __launch_bounds__(1024) void finalize_k(
    const float* __restrict__ rowsum, const float* __restrict__ pairsim,
    float* __restrict__ out) {
  float local = 0.0f;
  for (int i = threadIdx.x; i < NROWS; i += 1024)
    local += logf(rowsum[i]) - pairsim[i];
  #pragma unroll
  for (int off = 1; off < 64; off <<= 1) local += __shfl_xor(local, off);
  __shared__ float red[16];
  int wave = threadIdx.x >> 6;
  int lane = threadIdx.x & 63;
  if (lane == 0) red[wave] = local;
  __syncthreads();
  if (threadIdx.x == 0) {
    float s = 0.0f;
    #pragma unroll
    for (int w = 0; w < 16; ++w) s += red[w];
    out[0] = s * (1.0f / (float)NROWS);
  }
}

extern "C" void kernel_launch(void* const* d_in, const int* in_sizes, int n_in,
                              void* d_out, int out_size, void* d_ws, size_t ws_size,
                              hipStream_t stream) {
  const float* f1 = (const float*)d_in[0];
  const float* f2 = (const float*)d_in[1];
  ushort* Fn = (ushort*)d_ws;                                   // 8 MB bf16
  float* rowsum = (float*)((char*)d_ws + (size_t)NROWS * DIM * 2);
  float* pairsim = rowsum + NROWS;
  float* out = (float*)d_out;

  norm_cast_k<<<NROWS / 4, 256, 0, stream>>>(f1, f2, Fn, rowsum);
  sym_gemm_k<<<NBLOCKS, 256, 0, stream>>>(Fn, rowsum, pairsim);
  finalize_k<<<1, 1024, 0, stream>>>(rowsum, pairsim, out);
}